// Round 1
// baseline (855.161 us; speedup 1.0000x reference)
//
#include <hip/hip_runtime.h>
#include <stdint.h>

#define BB 2
#define NN 2048
#define CC 1024
#define HH 16
#define DD 64

typedef unsigned short ushort_t;
using u16x8  = __attribute__((ext_vector_type(8))) unsigned short;
using bf16x8 = __attribute__((ext_vector_type(8))) __bf16;
using f32x4  = __attribute__((ext_vector_type(4))) float;

__device__ __forceinline__ unsigned short f2b(float f) {
  union { float f; uint32_t u; } v; v.f = f;
  uint32_t u = v.u;
  return (unsigned short)((u + 0x7fffu + ((u >> 16) & 1u)) >> 16);
}

__device__ __forceinline__ f32x4 mfma_bf16(u16x8 a, u16x8 b, f32x4 c) {
  return __builtin_amdgcn_mfma_f32_16x16x32_bf16(
      __builtin_bit_cast(bf16x8, a), __builtin_bit_cast(bf16x8, b), c, 0, 0, 0);
}

#define GLD_LDS16(gp, lp)                                                        \
  __builtin_amdgcn_global_load_lds(                                              \
      (const __attribute__((address_space(1))) void*)(gp),                       \
      (__attribute__((address_space(3))) void*)(lp), 16, 0, 0)

// ---------------------------------------------------------------------------
// Fused fp32 -> bf16 cast of x, Wq, Wkv, Wo.  One float4 chunk per thread.
// chunk counts: x 1048576 | Wq 262144 | Wkv 524288 | Wo 262144  (total 2097152)
// ---------------------------------------------------------------------------
__global__ void cast_all(const float* __restrict__ x, const float* __restrict__ wq,
                         const float* __restrict__ wkv, const float* __restrict__ wo,
                         ushort_t* __restrict__ xb, ushort_t* __restrict__ wqb,
                         ushort_t* __restrict__ wkvb, ushort_t* __restrict__ wob) {
  int c = blockIdx.x * 256 + threadIdx.x;
  const float* src; ushort_t* dst; int off;
  if (c < 1048576)      { src = x;   dst = xb;   off = c; }
  else if (c < 1310720) { src = wq;  dst = wqb;  off = c - 1048576; }
  else if (c < 1835008) { src = wkv; dst = wkvb; off = c - 1310720; }
  else                  { src = wo;  dst = wob;  off = c - 1835008; }
  float4 v = *(const float4*)(src + (size_t)off * 4);
  ushort4 o;
  o.x = f2b(v.x); o.y = f2b(v.y); o.z = f2b(v.z); o.w = f2b(v.w);
  *(ushort4*)(dst + (size_t)off * 4) = o;
}

// ---------------------------------------------------------------------------
// Y[M x Nf] = A[M x K] @ W[Nf x K]^T   (both inputs bf16, K-contiguous)
// 128x128 tile, BK=64, 4 waves in 2x2, each wave 64x64 via 4x4 MFMA 16x16x32.
// F32OUT: fp32 store + bias (final proj); else bf16 store.
// ---------------------------------------------------------------------------
template <bool F32OUT>
__launch_bounds__(256, 2)
__global__ void gemm_bt(const ushort_t* __restrict__ A, const ushort_t* __restrict__ Bw,
                        void* __restrict__ out, const float* __restrict__ bo,
                        int M, int Nf, int K) {
  __shared__ __align__(16) ushort_t As[128 * 64];
  __shared__ __align__(16) ushort_t Bs[128 * 64];
  const int tid = threadIdx.x;
  const int w = tid >> 6, l = tid & 63;
  const int quad = l >> 4, l15 = l & 15;
  const int m0 = blockIdx.y * 128, n0 = blockIdx.x * 128;
  const int wm = (w >> 1) * 64, wn = (w & 1) * 64;

  const f32x4 zero = {0.f, 0.f, 0.f, 0.f};
  f32x4 acc[4][4];
  for (int i = 0; i < 4; ++i)
    for (int j = 0; j < 4; ++j) acc[i][j] = zero;

  for (int k0 = 0; k0 < K; k0 += 64) {
#pragma unroll
    for (int i = 0; i < 4; ++i) {
      int q = (i * 4 + w) * 64 + l;          // flat 16B-chunk id in tile
      int row = q >> 3, c8 = (q & 7) * 8;
      GLD_LDS16(A + (size_t)(m0 + row) * K + k0 + c8, As + (i * 4 + w) * 512);
      GLD_LDS16(Bw + (size_t)(n0 + row) * K + k0 + c8, Bs + (i * 4 + w) * 512);
    }
    __syncthreads();
#pragma unroll
    for (int s = 0; s < 2; ++s) {
      u16x8 af[4], bf[4];
#pragma unroll
      for (int mi = 0; mi < 4; ++mi)
        af[mi] = *(const u16x8*)(As + (wm + mi * 16 + l15) * 64 + s * 32 + quad * 8);
#pragma unroll
      for (int ni = 0; ni < 4; ++ni)
        bf[ni] = *(const u16x8*)(Bs + (wn + ni * 16 + l15) * 64 + s * 32 + quad * 8);
#pragma unroll
      for (int mi = 0; mi < 4; ++mi)
#pragma unroll
        for (int ni = 0; ni < 4; ++ni)
          acc[mi][ni] = mfma_bf16(af[mi], bf[ni], acc[mi][ni]);
    }
    __syncthreads();
  }

#pragma unroll
  for (int mi = 0; mi < 4; ++mi) {
#pragma unroll
    for (int ni = 0; ni < 4; ++ni) {
      int col = n0 + wn + ni * 16 + l15;
      float badd = F32OUT ? bo[col] : 0.f;
#pragma unroll
      for (int r = 0; r < 4; ++r) {
        int row = m0 + wm + mi * 16 + quad * 4 + r;   // C/D: row=quad*4+reg
        float v = acc[mi][ni][r] + badd;
        if (F32OUT) ((float*)out)[(size_t)row * Nf + col] = v;
        else        ((ushort_t*)out)[(size_t)row * Nf + col] = f2b(v);
      }
    }
  }
}

// ---------------------------------------------------------------------------
// Fused flash attention.  Grid (N/64, H, B), 256 threads = 4 waves.
// Wave w owns Q rows [q0 + 16w, q0 + 16w + 16); iterates 64-key tiles.
// ---------------------------------------------------------------------------
__launch_bounds__(256, 2)
__global__ void attn_fused(const ushort_t* __restrict__ qw,
                           const ushort_t* __restrict__ kvw,
                           const float* __restrict__ bias,
                           ushort_t* __restrict__ ao) {
  __shared__ __align__(16) ushort_t Qs[64 * 64];       // natural [row][dim]
  __shared__ __align__(16) ushort_t Ks[64 * 72];       // [key][dim], pad->72
  __shared__ __align__(16) ushort_t VTs[64 * 72];      // [dim][key], pad->72
  __shared__ __align__(16) ushort_t Ps[4 * 16 * 80];   // per-wave P, stride 80

  const int tid = threadIdx.x;
  const int w = tid >> 6, l = tid & 63;
  const int quad = l >> 4, l15 = l & 15;
  const int b = blockIdx.z, h = blockIdx.y;
  const int q0 = blockIdx.x * 64;

  // stage Q tile (wave w stages exactly its own 16 rows)
#pragma unroll
  for (int i = 0; i < 2; ++i) {
    int q = (w * 2 + i) * 64 + l;
    int row = q >> 3, c8 = (q & 7) * 8;
    GLD_LDS16(qw + ((size_t)(b * NN + q0 + row)) * CC + h * DD + c8,
              Qs + (w * 2 + i) * 512);
  }
  __syncthreads();

  u16x8 aq[2];
#pragma unroll
  for (int s = 0; s < 2; ++s)
    aq[s] = *(const u16x8*)(Qs + (w * 16 + l15) * 64 + s * 32 + quad * 8);

  const f32x4 zero = {0.f, 0.f, 0.f, 0.f};
  float m_run[4], l_run[4];
  f32x4 acc_o[4];
#pragma unroll
  for (int r = 0; r < 4; ++r) { m_run[r] = -1e30f; l_run[r] = 0.f; }
#pragma unroll
  for (int c = 0; c < 4; ++c) acc_o[c] = zero;

  const size_t bias_row0 = ((size_t)(b * HH + h)) * NN * NN;

  for (int kt = 0; kt < NN; kt += 64) {
    // stage K natural + V transposed (register path; padded strides)
#pragma unroll
    for (int i = 0; i < 2; ++i) {
      int chunk = i * 256 + tid;             // 0..511
      int key = chunk >> 3, c8 = (chunk & 7) * 8;
      const ushort_t* kp = kvw + ((size_t)(b * NN + kt + key)) * (2 * CC) + h * DD + c8;
      u16x8 k8 = *(const u16x8*)kp;
      *(u16x8*)(Ks + key * 72 + c8) = k8;
      u16x8 v8 = *(const u16x8*)(kp + CC);
#pragma unroll
      for (int j = 0; j < 8; ++j) VTs[(c8 + j) * 72 + key] = v8[j];
    }
    __syncthreads();

    // bias prefetch (fp32, C/D-layout coordinates)
    float bv[4][4];
#pragma unroll
    for (int c = 0; c < 4; ++c)
#pragma unroll
      for (int r = 0; r < 4; ++r)
        bv[c][r] = bias[bias_row0 + (size_t)(q0 + w * 16 + quad * 4 + r) * NN +
                        kt + c * 16 + l15];

    // S = Q K^T  (4 col-groups x 2 k-steps)
    f32x4 accs[4];
#pragma unroll
    for (int c = 0; c < 4; ++c) accs[c] = zero;
#pragma unroll
    for (int s = 0; s < 2; ++s)
#pragma unroll
      for (int c = 0; c < 4; ++c) {
        u16x8 bk = *(const u16x8*)(Ks + (c * 16 + l15) * 72 + s * 32 + quad * 8);
        accs[c] = mfma_bf16(aq[s], bk, accs[c]);
      }

    // online softmax; quad owns rows quad*4 + r
#pragma unroll
    for (int r = 0; r < 4; ++r) {
      float sv[4];
      float mx = -1e30f;
#pragma unroll
      for (int c = 0; c < 4; ++c) {
        sv[c] = accs[c][r] * 0.125f + bv[c][r];
        mx = fmaxf(mx, sv[c]);
      }
#pragma unroll
      for (int off = 1; off < 16; off <<= 1)
        mx = fmaxf(mx, __shfl_xor(mx, off, 64));
      float mnew = fmaxf(m_run[r], mx);
      float alpha = __expf(m_run[r] - mnew);
      m_run[r] = mnew;
      float sum = 0.f;
#pragma unroll
      for (int c = 0; c < 4; ++c) {
        float pv = __expf(sv[c] - mnew);
        sum += pv;
        Ps[w * 1280 + (quad * 4 + r) * 80 + c * 16 + l15] = f2b(pv);
      }
#pragma unroll
      for (int off = 1; off < 16; off <<= 1)
        sum += __shfl_xor(sum, off, 64);
      l_run[r] = l_run[r] * alpha + sum;
#pragma unroll
      for (int c = 0; c < 4; ++c) acc_o[c][r] *= alpha;
    }

    // O += P V   (P from LDS in A-layout, V^T gives contiguous b-frags)
#pragma unroll
    for (int s = 0; s < 2; ++s) {
      u16x8 ap = *(const u16x8*)(Ps + w * 1280 + l15 * 80 + s * 32 + quad * 8);
#pragma unroll
      for (int c = 0; c < 4; ++c) {
        u16x8 vb = *(const u16x8*)(VTs + (c * 16 + l15) * 72 + s * 32 + quad * 8);
        acc_o[c] = mfma_bf16(ap, vb, acc_o[c]);
      }
    }
    __syncthreads();   // protect Ks/VTs for next tile
  }

  // epilogue: normalize, store bf16 to attn_out (token-major, feature = h*64+d)
#pragma unroll
  for (int c = 0; c < 4; ++c)
#pragma unroll
    for (int r = 0; r < 4; ++r) {
      float v = acc_o[c][r] / l_run[r];
      int row = q0 + w * 16 + quad * 4 + r;
      ao[((size_t)(b * NN + row)) * CC + h * DD + c * 16 + l15] = f2b(v);
    }
}

// ---------------------------------------------------------------------------
extern "C" void kernel_launch(void* const* d_in, const int* in_sizes, int n_in,
                              void* d_out, int out_size, void* d_ws, size_t ws_size,
                              hipStream_t stream) {
  const float* x    = (const float*)d_in[0];
  const float* bias = (const float*)d_in[1];
  const float* Wq   = (const float*)d_in[2];
  const float* Wkv  = (const float*)d_in[3];
  const float* Wo   = (const float*)d_in[4];
  const float* bo   = (const float*)d_in[5];
  float* out = (float*)d_out;

  // workspace layout (bf16 elements): 48 MB total
  ushort_t* xb   = (ushort_t*)d_ws;
  ushort_t* wqb  = xb   + (size_t)4194304;  // x cast
  ushort_t* wkvb = wqb  + (size_t)1048576;
  ushort_t* wob  = wkvb + (size_t)2097152;
  ushort_t* qws  = wob  + (size_t)1048576;  // Q  [4096 x 1024]
  ushort_t* kvws = qws  + (size_t)4194304;  // KV [4096 x 2048]
  ushort_t* aow  = kvws + (size_t)8388608;  // attn out [4096 x 1024]

  cast_all<<<8192, 256, 0, stream>>>(x, Wq, Wkv, Wo, xb, wqb, wkvb, wob);
  gemm_bt<false><<<dim3(8, 32), 256, 0, stream>>>(xb, wqb, qws, nullptr, 4096, 1024, 1024);
  gemm_bt<false><<<dim3(16, 32), 256, 0, stream>>>(xb, wkvb, kvws, nullptr, 4096, 2048, 1024);
  attn_fused<<<dim3(32, 16, 2), 256, 0, stream>>>(qws, kvws, bias, aow);
  gemm_bt<true><<<dim3(8, 32), 256, 0, stream>>>(aow, wob, out, bo, 4096, 1024, 1024);
}

// Round 2
// 824.971 us; speedup vs baseline: 1.0366x; 1.0366x over previous
//
#include <hip/hip_runtime.h>
#include <stdint.h>

#define BB 2
#define NN 2048
#define CC 1024
#define HH 16
#define DD 64

typedef unsigned short ushort_t;
using u16x8  = __attribute__((ext_vector_type(8))) unsigned short;
using bf16x8 = __attribute__((ext_vector_type(8))) __bf16;
using f32x4  = __attribute__((ext_vector_type(4))) float;

__device__ __forceinline__ unsigned short f2b(float f) {
  union { float f; uint32_t u; } v; v.f = f;
  uint32_t u = v.u;
  return (unsigned short)((u + 0x7fffu + ((u >> 16) & 1u)) >> 16);
}

__device__ __forceinline__ f32x4 mfma_bf16(u16x8 a, u16x8 b, f32x4 c) {
  return __builtin_amdgcn_mfma_f32_16x16x32_bf16(
      __builtin_bit_cast(bf16x8, a), __builtin_bit_cast(bf16x8, b), c, 0, 0, 0);
}

#define GLD_LDS16(gp, lp)                                                        \
  __builtin_amdgcn_global_load_lds(                                              \
      (const __attribute__((address_space(1))) void*)(gp),                       \
      (__attribute__((address_space(3))) void*)(lp), 16, 0, 0)

// XOR swizzle: 16B chunk `c` of 128B row `r` lives at LDS slot c ^ (r&7).
// Staging stays linear (global source permuted); frag reads at slot
// (4s+quad)^(l15&7) cover all 8 bank-quads -> conflict-free ds_read_b128.

// ---------------------------------------------------------------------------
// Fused fp32 -> bf16 cast of x, Wq, Wkv, Wo.  One float4 chunk per thread.
// ---------------------------------------------------------------------------
__global__ void cast_all(const float* __restrict__ x, const float* __restrict__ wq,
                         const float* __restrict__ wkv, const float* __restrict__ wo,
                         ushort_t* __restrict__ xb, ushort_t* __restrict__ wqb,
                         ushort_t* __restrict__ wkvb, ushort_t* __restrict__ wob) {
  int c = blockIdx.x * 256 + threadIdx.x;
  const float* src; ushort_t* dst; int off;
  if (c < 1048576)      { src = x;   dst = xb;   off = c; }
  else if (c < 1310720) { src = wq;  dst = wqb;  off = c - 1048576; }
  else if (c < 1835008) { src = wkv; dst = wkvb; off = c - 1310720; }
  else                  { src = wo;  dst = wob;  off = c - 1835008; }
  float4 v = *(const float4*)(src + (size_t)off * 4);
  ushort4 o;
  o.x = f2b(v.x); o.y = f2b(v.y); o.z = f2b(v.z); o.w = f2b(v.w);
  *(ushort4*)(dst + (size_t)off * 4) = o;
}

// ---------------------------------------------------------------------------
// Y[M x Nf] = A[M x K] @ W[Nf x K]^T   (bf16 in, K-contiguous)
// 128x128 tile, BK=64, 4 waves 2x2, wave = 64x64 via 4x4 MFMA 16x16x32.
// MODE 0: bf16 out (stride Nf). MODE 1: fp32 out + bias. MODE 2: kv-split —
//   cols <1024 -> K natural (stride 1024); cols >=1024 -> V^T [b*1024+d][token].
// ---------------------------------------------------------------------------
template <int MODE>
__launch_bounds__(256, 2)
__global__ void gemm_bt(const ushort_t* __restrict__ A, const ushort_t* __restrict__ Bw,
                        void* __restrict__ out, ushort_t* __restrict__ vtw,
                        const float* __restrict__ bo, int M, int Nf, int K) {
  __shared__ __align__(16) ushort_t As[128 * 64];
  __shared__ __align__(16) ushort_t Bs[128 * 64];
  const int tid = threadIdx.x;
  const int w = tid >> 6, l = tid & 63;
  const int quad = l >> 4, l15 = l & 15;
  const int m0 = blockIdx.y * 128, n0 = blockIdx.x * 128;
  const int wm = (w >> 1) * 64, wn = (w & 1) * 64;

  const f32x4 zero = {0.f, 0.f, 0.f, 0.f};
  f32x4 acc[4][4];
  for (int i = 0; i < 4; ++i)
    for (int j = 0; j < 4; ++j) acc[i][j] = zero;

  for (int k0 = 0; k0 < K; k0 += 64) {
#pragma unroll
    for (int i = 0; i < 4; ++i) {
      int q = (i * 4 + w) * 64 + l;          // flat 16B-slot id in tile
      int row = q >> 3;
      int gc = (q & 7) ^ (row & 7);          // swizzle: slot q&7 holds chunk gc
      GLD_LDS16(A + (size_t)(m0 + row) * K + k0 + gc * 8, As + (i * 4 + w) * 512);
      GLD_LDS16(Bw + (size_t)(n0 + row) * K + k0 + gc * 8, Bs + (i * 4 + w) * 512);
    }
    __syncthreads();
#pragma unroll
    for (int s = 0; s < 2; ++s) {
      u16x8 af[4], bf4[4];
      const int slot = ((4 * s + quad) ^ (l15 & 7)) * 8;
#pragma unroll
      for (int mi = 0; mi < 4; ++mi)
        af[mi] = *(const u16x8*)(As + (wm + mi * 16 + l15) * 64 + slot);
#pragma unroll
      for (int ni = 0; ni < 4; ++ni)
        bf4[ni] = *(const u16x8*)(Bs + (wn + ni * 16 + l15) * 64 + slot);
#pragma unroll
      for (int mi = 0; mi < 4; ++mi)
#pragma unroll
        for (int ni = 0; ni < 4; ++ni)
          acc[mi][ni] = mfma_bf16(af[mi], bf4[ni], acc[mi][ni]);
    }
    __syncthreads();
  }

  if (MODE == 2 && n0 >= 1024) {
    // V columns -> vtw transposed: vtw[(b*1024 + d)][token], ushort4 per frag
#pragma unroll
    for (int mi = 0; mi < 4; ++mi) {
#pragma unroll
      for (int ni = 0; ni < 4; ++ni) {
        int d = n0 + wn + ni * 16 + l15 - 1024;
        int row = m0 + wm + mi * 16 + quad * 4;       // 4 consecutive tokens
        int b = row >> 11, n = row & 2047;
        ushort4 p;
        p.x = f2b(acc[mi][ni][0]); p.y = f2b(acc[mi][ni][1]);
        p.z = f2b(acc[mi][ni][2]); p.w = f2b(acc[mi][ni][3]);
        *(ushort4*)(vtw + ((size_t)(b * 1024 + d)) * 2048 + n) = p;
      }
    }
    return;
  }

#pragma unroll
  for (int mi = 0; mi < 4; ++mi) {
#pragma unroll
    for (int ni = 0; ni < 4; ++ni) {
      int col = n0 + wn + ni * 16 + l15;
      float badd = (MODE == 1) ? bo[col] : 0.f;
#pragma unroll
      for (int r = 0; r < 4; ++r) {
        int row = m0 + wm + mi * 16 + quad * 4 + r;   // C/D: row=quad*4+reg
        float v = acc[mi][ni][r] + badd;
        if (MODE == 1)      ((float*)out)[(size_t)row * Nf + col] = v;
        else if (MODE == 2) ((ushort_t*)out)[(size_t)row * 1024 + col] = f2b(v);
        else                ((ushort_t*)out)[(size_t)row * Nf + col] = f2b(v);
      }
    }
  }
}

// ---------------------------------------------------------------------------
// Fused flash attention.  Grid (N/64, H, B), 256 threads = 4 waves.
// Wave w owns Q rows [q0+16w, q0+16w+16); iterates 64-key tiles.
// K natural [token][C] from kws; V^T [b*1024+h*64+d][token] from vtw.
// ---------------------------------------------------------------------------
__launch_bounds__(256, 2)
__global__ void attn_fused(const ushort_t* __restrict__ qw,
                           const ushort_t* __restrict__ kw,
                           const ushort_t* __restrict__ vtg,
                           const float* __restrict__ bias,
                           ushort_t* __restrict__ ao) {
  __shared__ __align__(16) ushort_t Qs[64 * 64];       // [qrow][dim], swizzled
  __shared__ __align__(16) ushort_t Ks[64 * 64];       // [key][dim], swizzled
  __shared__ __align__(16) ushort_t VTs[64 * 64];      // [dim][key], swizzled
  __shared__ __align__(16) ushort_t Ps[4 * 16 * 88];   // per-wave P, stride 88

  const int tid = threadIdx.x;
  const int w = tid >> 6, l = tid & 63;
  const int quad = l >> 4, l15 = l & 15;
  const int b = blockIdx.z, h = blockIdx.y;
  const int q0 = blockIdx.x * 64;

  const ushort_t* vbase = vtg + ((size_t)(b * 1024 + h * 64)) * NN;

  // stage Q tile (wave w stages its own 16 rows), swizzled
#pragma unroll
  for (int i = 0; i < 2; ++i) {
    int q = (w * 2 + i) * 64 + l;
    int row = q >> 3;
    int gc = (q & 7) ^ (row & 7);
    GLD_LDS16(qw + ((size_t)(b * NN + q0 + row)) * CC + h * DD + gc * 8,
              Qs + (w * 2 + i) * 512);
  }
  __syncthreads();

  u16x8 aq[2];
#pragma unroll
  for (int s = 0; s < 2; ++s)
    aq[s] = *(const u16x8*)(Qs + (w * 16 + l15) * 64 + (((4 * s + quad) ^ (l15 & 7)) * 8));

  const f32x4 zero = {0.f, 0.f, 0.f, 0.f};
  float m_run[4], l_run[4];
  f32x4 acc_o[4];
#pragma unroll
  for (int r = 0; r < 4; ++r) { m_run[r] = -1e30f; l_run[r] = 0.f; }
#pragma unroll
  for (int c = 0; c < 4; ++c) acc_o[c] = zero;

  const size_t bias_row0 = ((size_t)(b * HH + h)) * NN * NN;

  for (int kt = 0; kt < NN; kt += 64) {
    // stage K (rows=keys) and V^T (rows=dims), both swizzled via GLD
#pragma unroll
    for (int i = 0; i < 2; ++i) {
      int q = i * 256 + tid;                 // 0..511
      int row = q >> 3;
      int gc = (q & 7) ^ (row & 7);
      GLD_LDS16(kw + ((size_t)(b * NN + kt + row)) * CC + h * DD + gc * 8,
                Ks + i * 2048 + w * 512);
      GLD_LDS16(vbase + (size_t)row * NN + kt + gc * 8,
                VTs + i * 2048 + w * 512);
    }
    __syncthreads();

    // bias prefetch (fp32, C/D-layout coordinates)
    float bv[4][4];
#pragma unroll
    for (int c = 0; c < 4; ++c)
#pragma unroll
      for (int r = 0; r < 4; ++r)
        bv[c][r] = bias[bias_row0 + (size_t)(q0 + w * 16 + quad * 4 + r) * NN +
                        kt + c * 16 + l15];

    // S = Q K^T
    f32x4 accs[4];
#pragma unroll
    for (int c = 0; c < 4; ++c) accs[c] = zero;
#pragma unroll
    for (int s = 0; s < 2; ++s) {
      const int slot = ((4 * s + quad) ^ (l15 & 7)) * 8;
#pragma unroll
      for (int c = 0; c < 4; ++c) {
        u16x8 bk = *(const u16x8*)(Ks + (c * 16 + l15) * 64 + slot);
        accs[c] = mfma_bf16(aq[s], bk, accs[c]);
      }
    }

    // online softmax; quad owns rows quad*4 + r
#pragma unroll
    for (int r = 0; r < 4; ++r) {
      float sv[4];
      float mx = -1e30f;
#pragma unroll
      for (int c = 0; c < 4; ++c) {
        sv[c] = accs[c][r] * 0.125f + bv[c][r];
        mx = fmaxf(mx, sv[c]);
      }
#pragma unroll
      for (int off = 1; off < 16; off <<= 1)
        mx = fmaxf(mx, __shfl_xor(mx, off, 64));
      float mnew = fmaxf(m_run[r], mx);
      float alpha = __expf(m_run[r] - mnew);
      m_run[r] = mnew;
      float sum = 0.f;
#pragma unroll
      for (int c = 0; c < 4; ++c) {
        float pv = __expf(sv[c] - mnew);
        sum += pv;
        Ps[w * 1408 + (quad * 4 + r) * 88 + c * 16 + l15] = f2b(pv);
      }
#pragma unroll
      for (int off = 1; off < 16; off <<= 1)
        sum += __shfl_xor(sum, off, 64);
      l_run[r] = l_run[r] * alpha + sum;
#pragma unroll
      for (int c = 0; c < 4; ++c) acc_o[c][r] *= alpha;
    }

    // O += P V   (P per-wave in LDS A-layout; V^T swizzled b-frags)
#pragma unroll
    for (int s = 0; s < 2; ++s) {
      u16x8 ap = *(const u16x8*)(Ps + w * 1408 + l15 * 88 + s * 32 + quad * 8);
      const int slot = ((4 * s + quad) ^ (l15 & 7)) * 8;
#pragma unroll
      for (int c = 0; c < 4; ++c) {
        u16x8 vb = *(const u16x8*)(VTs + (c * 16 + l15) * 64 + slot);
        acc_o[c] = mfma_bf16(ap, vb, acc_o[c]);
      }
    }
    __syncthreads();   // protect Ks/VTs for next tile
  }

  // epilogue: normalize, store bf16 (token-major, feature = h*64+d)
#pragma unroll
  for (int c = 0; c < 4; ++c)
#pragma unroll
    for (int r = 0; r < 4; ++r) {
      float v = acc_o[c][r] / l_run[r];
      int row = q0 + w * 16 + quad * 4 + r;
      ao[((size_t)(b * NN + row)) * CC + h * DD + c * 16 + l15] = f2b(v);
    }
}

// ---------------------------------------------------------------------------
extern "C" void kernel_launch(void* const* d_in, const int* in_sizes, int n_in,
                              void* d_out, int out_size, void* d_ws, size_t ws_size,
                              hipStream_t stream) {
  const float* x    = (const float*)d_in[0];
  const float* bias = (const float*)d_in[1];
  const float* Wq   = (const float*)d_in[2];
  const float* Wkv  = (const float*)d_in[3];
  const float* Wo   = (const float*)d_in[4];
  const float* bo   = (const float*)d_in[5];
  float* out = (float*)d_out;

  // workspace layout (bf16 elements): ~50.3 MB total
  ushort_t* xb   = (ushort_t*)d_ws;
  ushort_t* wqb  = xb   + (size_t)4194304;
  ushort_t* wkvb = wqb  + (size_t)1048576;
  ushort_t* wob  = wkvb + (size_t)2097152;
  ushort_t* qws  = wob  + (size_t)1048576;  // Q   [4096 x 1024]
  ushort_t* kws  = qws  + (size_t)4194304;  // K   [4096 x 1024]
  ushort_t* vtw  = kws  + (size_t)4194304;  // V^T [2048 x 2048] = [(b,h,d)][tok]
  ushort_t* aow  = vtw  + (size_t)4194304;  // attn out [4096 x 1024]

  cast_all<<<8192, 256, 0, stream>>>(x, Wq, Wkv, Wo, xb, wqb, wkvb, wob);
  gemm_bt<0><<<dim3(8, 32), 256, 0, stream>>>(xb, wqb, qws, nullptr, nullptr, 4096, 1024, 1024);
  gemm_bt<2><<<dim3(16, 32), 256, 0, stream>>>(xb, wkvb, kws, vtw, nullptr, 4096, 2048, 1024);
  attn_fused<<<dim3(32, 16, 2), 256, 0, stream>>>(qws, kws, vtw, bias, aow);
  gemm_bt<1><<<dim3(8, 32), 256, 0, stream>>>(aow, wob, out, nullptr, bo, 4096, 1024, 1024);
}